// Round 2
// baseline (203.561 us; speedup 1.0000x reference)
//
#include <hip/hip_runtime.h>

#define BATCH 512
#define SEQ   512
#define VOCAB 1000
#define EMB   100
#define UNITS 64
#define RPW   2   // rows (independent recurrences) per wave

typedef float v2f __attribute__((ext_vector_type(2)));

// ---------------------------------------------------------------------------
// Kernel 1: P[v][u] = 2*(sum_d emb[v][d] * Wxh[d][u] + b[u])   (VOCAB x UNITS)
// x2 pre-scale is an exact power-of-2 (commutes with fp rounding): the scan
// feeds y directly into exp(y) for tanh(s)=1-2/(exp(2s)+1), saving a
// dependent v_mul per step.
// ---------------------------------------------------------------------------
__global__ __launch_bounds__(64) void proj_kernel(
    const float* __restrict__ emb, const float* __restrict__ Wxh,
    const float* __restrict__ bias, float* __restrict__ P) {
  const int v = blockIdx.x;
  const int u = threadIdx.x;
  const float* e = emb + v * EMB;
  float acc = bias[u];
#pragma unroll 5
  for (int d = 0; d < EMB; ++d) acc += e[d] * Wxh[d * UNITS + u];
  P[v * UNITS + u] = 2.f * acc;
}

// ---------------------------------------------------------------------------
// DPP all-gather of one value/lane across the lane's own 16-lane row.
// 4 quad_perm broadcasts cover the quad, row_ror 4/8/12 cover the other 3
// quads, for EITHER rotate direction; the exact slot->source-lane permutation
// is discovered at runtime (calibration on lane_id) and folded into the
// weight layout.
// ---------------------------------------------------------------------------
#define DPP_I(src, ctrl) __builtin_amdgcn_update_dpp(0, (src), (ctrl), 0xF, 0xF, true)

#define GATHER_ROW(v_, g_)                                          \
  do {                                                              \
    g_[0] = DPP_I((v_), 0x00);  /* quad_perm:[0,0,0,0] */           \
    g_[1] = DPP_I((v_), 0x55);  /* quad_perm:[1,1,1,1] */           \
    g_[2] = DPP_I((v_), 0xAA);  /* quad_perm:[2,2,2,2] */           \
    g_[3] = DPP_I((v_), 0xFF);  /* quad_perm:[3,3,3,3] */           \
    g_[4]  = DPP_I(g_[0], 0x124); g_[5]  = DPP_I(g_[1], 0x124);     \
    g_[6]  = DPP_I(g_[2], 0x124); g_[7]  = DPP_I(g_[3], 0x124);     \
    g_[8]  = DPP_I(g_[0], 0x128); g_[9]  = DPP_I(g_[1], 0x128);     \
    g_[10] = DPP_I(g_[2], 0x128); g_[11] = DPP_I(g_[3], 0x128);     \
    g_[12] = DPP_I(g_[0], 0x12C); g_[13] = DPP_I(g_[1], 0x12C);     \
    g_[14] = DPP_I(g_[2], 0x12C); g_[15] = DPP_I(g_[3], 0x12C);     \
  } while (0)

// lane^16 / lane^32 exchange on the VALU pipe; 'sel' calibrated once.
__device__ __forceinline__ float sw16(float v, bool sel) {
  int x = __float_as_int(v), y = x;
  asm volatile("s_nop 1\n\tv_permlane16_swap_b32 %0, %1" : "+v"(x), "+v"(y));
  return sel ? __int_as_float(x) : __int_as_float(y);
}
__device__ __forceinline__ float sw32(float v, bool sel) {
  int x = __float_as_int(v), y = x;
  asm volatile("s_nop 1\n\tv_permlane32_swap_b32 %0, %1" : "+v"(x), "+v"(y));
  return sel ? __int_as_float(x) : __int_as_float(y);
}

// ---------------------------------------------------------------------------
// Kernel 2: sequential scan, TWO independent rows per wave. Register-only
// h-broadcast (DPP row gather + permlane combines). The two rows share the
// Whh weight registers; their dependency chains are independent, so each
// row's instructions issue in the other row's latency stalls (single wave
// per SIMD: there is no other wave to fill them).
// ---------------------------------------------------------------------------
__global__ __launch_bounds__(64)
__attribute__((amdgpu_waves_per_eu(1, 1)))
void scan_kernel(
    const int* __restrict__ tok, const float* __restrict__ P,
    const float* __restrict__ Whh, const float* __restrict__ Wout,
    const float* __restrict__ bout, float* __restrict__ out) {
  const int row0 = blockIdx.x * RPW;
  const int lane = threadIdx.x;

  // ---- calibration: gather permutation + swap register-select ----
  int gcal[16];
  GATHER_ROW(lane, gcal);  // gcal[s] = source lane (== unit index) of slot s

  int x16 = lane, y16 = lane;
  asm volatile("s_nop 1\n\tv_permlane16_swap_b32 %0, %1" : "+v"(x16), "+v"(y16));
  const bool sel16 = (x16 == (lane ^ 16));
  int x32 = lane, y32 = lane;
  asm volatile("s_nop 1\n\tv_permlane32_swap_b32 %0, %1" : "+v"(x32), "+v"(y32));
  const bool sel32 = (x32 == (lane ^ 32));

  // ---- weights: 4 columns (lane, ^16, ^32, ^48) x own-row 16 inputs,
  // permuted to gather order, pre-scaled x2, pinned in VGPRs. SHARED by
  // both rows. ----
  const int c0 = lane, c1 = lane ^ 16, c2 = lane ^ 32, c3 = lane ^ 48;
  v2f w0[8], w1[8], w2[8], w3[8];
#pragma unroll
  for (int s = 0; s < 8; ++s) {
    const int i0 = gcal[2 * s] * UNITS, i1 = gcal[2 * s + 1] * UNITS;
    float t00 = 2.f * Whh[i0 + c0], t01 = 2.f * Whh[i1 + c0];
    float t10 = 2.f * Whh[i0 + c1], t11 = 2.f * Whh[i1 + c1];
    float t20 = 2.f * Whh[i0 + c2], t21 = 2.f * Whh[i1 + c2];
    float t30 = 2.f * Whh[i0 + c3], t31 = 2.f * Whh[i1 + c3];
    asm volatile("" : "+v"(t00), "+v"(t01), "+v"(t10), "+v"(t11));
    asm volatile("" : "+v"(t20), "+v"(t21), "+v"(t30), "+v"(t31));
    w0[s].x = t00; w0[s].y = t01;  w1[s].x = t10; w1[s].y = t11;
    w2[s].x = t20; w2[s].y = t21;  w3[s].x = t30; w3[s].y = t31;
  }

  // ---- tokens for both rows, pre-scaled by UNITS (coalesced) ----
  int tokA[SEQ / 64], tokB[SEQ / 64];
  const int* trowA = tok + (long)row0 * SEQ;
  const int* trowB = tok + (long)(row0 + 1) * SEQ;
#pragma unroll
  for (int c = 0; c < SEQ / 64; ++c) {
    int ta = trowA[c * 64 + lane] * UNITS;
    int tb = trowB[c * 64 + lane] * UNITS;
    asm volatile("" : "+v"(ta), "+v"(tb));
    tokA[c] = ta;
    tokB[c] = tb;
  }

  float hA = 0.f, hB = 0.f;

  // distance-2 P prefetch rings (one per row).
  float a0A = P[(long)__builtin_amdgcn_readlane(tokA[0], 0) + lane];
  float a1A = P[(long)__builtin_amdgcn_readlane(tokA[0], 1) + lane];
  float a0B = P[(long)__builtin_amdgcn_readlane(tokB[0], 0) + lane];
  float a1B = P[(long)__builtin_amdgcn_readlane(tokB[0], 1) + lane];

#pragma unroll
  for (int c = 0; c < SEQ / 64; ++c) {
#pragma unroll 2
    for (int tt = 0; tt < 64; ++tt) {
      float acA = a0A; a0A = a1A;
      float acB = a0B; a0B = a1B;
      int tknA = __builtin_amdgcn_readlane(tokA[c], (tt + 2) & 63);
      int tknB = __builtin_amdgcn_readlane(tokB[c], (tt + 2) & 63);
      a1A = P[(long)tknA + lane];  // garbage at tt=62,63; patched below
      a1B = P[(long)tknB + lane];

      // ---- in-register all-gather of h across own 16-lane row, both rows ----
      int giA[16], giB[16];
      GATHER_ROW(__float_as_int(hA), giA);
      GATHER_ROW(__float_as_int(hB), giB);

      // ---- 4 column partials per row; the 8 accumulator chains are
      // mutually independent -> B fills A's fma-latency bubbles ----
      v2f aA0, aA1 = {0.f, 0.f}, aA2 = {0.f, 0.f}, aA3 = {0.f, 0.f};
      v2f aB0, aB1 = {0.f, 0.f}, aB2 = {0.f, 0.f}, aB3 = {0.f, 0.f};
      aA0.x = acA; aA0.y = 0.f;
      aB0.x = acB; aB0.y = 0.f;
#pragma unroll
      for (int s = 0; s < 8; ++s) {
        v2f gA, gB;
        gA.x = __int_as_float(giA[2 * s]);
        gA.y = __int_as_float(giA[2 * s + 1]);
        gB.x = __int_as_float(giB[2 * s]);
        gB.y = __int_as_float(giB[2 * s + 1]);
        aA0 += gA * w0[s];  aB0 += gB * w0[s];
        aA1 += gA * w1[s];  aB1 += gB * w1[s];
        aA2 += gA * w2[s];  aB2 += gB * w2[s];
        aA3 += gA * w3[s];  aB3 += gB * w3[s];
      }
      float pA0 = aA0.x + aA0.y, pA1 = aA1.x + aA1.y;
      float pA2 = aA2.x + aA2.y, pA3 = aA3.x + aA3.y;
      float pB0 = aB0.x + aB0.y, pB1 = aB1.x + aB1.y;
      float pB2 = aB2.x + aB2.y, pB3 = aB3.x + aB3.y;

      // combine: y[j] = P0(j) + P1(j^16) + P2(j^32) + P3(j^48)
      float s1A = pA0 + sw16(pA1, sel16);
      float s2A = pA2 + sw16(pA3, sel16);
      float s1B = pB0 + sw16(pB1, sel16);
      float s2B = pB2 + sw16(pB3, sel16);
      float yA = s1A + sw32(s2A, sel32);
      float yB = s1B + sw32(s2B, sel32);

      // tanh(s) = 1 - 2/(exp(2s)+1); y is already 2s
      float eA = __expf(yA);
      float eB = __expf(yB);
      hA = 1.f - 2.f / (eA + 1.f);
      hB = 1.f - 2.f / (eB + 1.f);
    }
    if (c + 1 < SEQ / 64) {  // restore ring invariant for next chunk
      a0A = P[(long)__builtin_amdgcn_readlane(tokA[c + 1], 0) + lane];
      a1A = P[(long)__builtin_amdgcn_readlane(tokA[c + 1], 1) + lane];
      a0B = P[(long)__builtin_amdgcn_readlane(tokB[c + 1], 0) + lane];
      a1B = P[(long)__builtin_amdgcn_readlane(tokB[c + 1], 1) + lane];
    }
  }

  // out[row] = sigmoid(sum_j h[j]*Wout[j] + bout), both rows
  float pA = hA * Wout[lane];
  float pB = hB * Wout[lane];
#pragma unroll
  for (int off = 32; off > 0; off >>= 1) {
    pA += __shfl_xor(pA, off);
    pB += __shfl_xor(pB, off);
  }
  if (lane == 0) {
    float b0 = bout[0];
    out[row0]     = 1.f / (1.f + __expf(-(pA + b0)));
    out[row0 + 1] = 1.f / (1.f + __expf(-(pB + b0)));
  }
}

extern "C" void kernel_launch(void* const* d_in, const int* in_sizes, int n_in,
                              void* d_out, int out_size, void* d_ws, size_t ws_size,
                              hipStream_t stream) {
  const int*   tok  = (const int*)  d_in[0];  // [BATCH, SEQ] int32
  const float* emb  = (const float*)d_in[1];  // [VOCAB, EMB]
  const float* Wxh  = (const float*)d_in[2];  // [EMB, UNITS]
  const float* Whh  = (const float*)d_in[3];  // [UNITS, UNITS]
  const float* bias = (const float*)d_in[4];  // [UNITS]
  const float* Wout = (const float*)d_in[5];  // [UNITS, 1]
  const float* bout = (const float*)d_in[6];  // [1]
  float* out = (float*)d_out;                 // [BATCH, 1] fp32

  float* P = (float*)d_ws;                    // VOCAB*UNITS fp32 = 256 KB

  proj_kernel<<<VOCAB, 64, 0, stream>>>(emb, Wxh, bias, P);
  scan_kernel<<<BATCH / RPW, 64, 0, stream>>>(tok, P, Whh, Wout, bout, out);
}

// Round 3
// 172.411 us; speedup vs baseline: 1.1807x; 1.1807x over previous
//
#include <hip/hip_runtime.h>

#define BATCH 512
#define SEQ   512
#define VOCAB 1000
#define EMB   100
#define UNITS 64
#define WPB   8                      // waves per block -> 2 waves per SIMD (SMT hedge)
#define SC    2.88539008177792681f   // 2*log2(e): v_exp_f32(SC*s) == e^{2s}

typedef float v2f __attribute__((ext_vector_type(2)));

// ---------------------------------------------------------------------------
// Kernel 1: P[v][u] = SC*(sum_d emb[v][d] * Wxh[d][u] + b[u])   (VOCAB x UNITS)
// SC = 2*log2(e) pre-scale: the scan feeds y straight into v_exp_f32 (2^y)
// for tanh(s) = 1 - 2/(e^{2s}+1), removing the dependent mul before exp.
// ---------------------------------------------------------------------------
__global__ __launch_bounds__(64) void proj_kernel(
    const float* __restrict__ emb, const float* __restrict__ Wxh,
    const float* __restrict__ bias, float* __restrict__ P) {
  const int v = blockIdx.x;
  const int u = threadIdx.x;
  const float* e = emb + v * EMB;
  float acc = bias[u];
#pragma unroll 5
  for (int d = 0; d < EMB; ++d) acc += e[d] * Wxh[d * UNITS + u];
  P[v * UNITS + u] = SC * acc;
}

// ---------------------------------------------------------------------------
// DPP all-gather of one value/lane across the lane's own 16-lane row.
// 4 quad_perm broadcasts + row_ror 4/8/12 cover all 16 row values for EITHER
// rotate direction; exact slot->source-lane permutation is calibrated at
// runtime (on lane_id) and folded into the weight layout.
// ---------------------------------------------------------------------------
#define DPP_I(src, ctrl) __builtin_amdgcn_update_dpp(0, (src), (ctrl), 0xF, 0xF, true)

#define GATHER_ROW(v_, g_)                                          \
  do {                                                              \
    g_[0] = DPP_I((v_), 0x00);  /* quad_perm:[0,0,0,0] */           \
    g_[1] = DPP_I((v_), 0x55);  /* quad_perm:[1,1,1,1] */           \
    g_[2] = DPP_I((v_), 0xAA);  /* quad_perm:[2,2,2,2] */           \
    g_[3] = DPP_I((v_), 0xFF);  /* quad_perm:[3,3,3,3] */           \
    g_[4]  = DPP_I(g_[0], 0x124); g_[5]  = DPP_I(g_[1], 0x124);     \
    g_[6]  = DPP_I(g_[2], 0x124); g_[7]  = DPP_I(g_[3], 0x124);     \
    g_[8]  = DPP_I(g_[0], 0x128); g_[9]  = DPP_I(g_[1], 0x128);     \
    g_[10] = DPP_I(g_[2], 0x128); g_[11] = DPP_I(g_[3], 0x128);     \
    g_[12] = DPP_I(g_[0], 0x12C); g_[13] = DPP_I(g_[1], 0x12C);     \
    g_[14] = DPP_I(g_[2], 0x12C); g_[15] = DPP_I(g_[3], 0x12C);     \
  } while (0)

// lane^16 / lane^32 exchange on the VALU pipe; duplicate-then-swap guarantees
// (for any block-swap semantics) that each lane holds the partner value in
// exactly one of the two regs; 'sel' (calibrated on lane_id) picks it.
__device__ __forceinline__ float sw16(float v, bool sel) {
  int x = __float_as_int(v), y = x;
  asm volatile("s_nop 1\n\tv_permlane16_swap_b32 %0, %1" : "+v"(x), "+v"(y));
  return sel ? __int_as_float(x) : __int_as_float(y);
}
__device__ __forceinline__ float sw32(float v, bool sel) {
  int x = __float_as_int(v), y = x;
  asm volatile("s_nop 1\n\tv_permlane32_swap_b32 %0, %1" : "+v"(x), "+v"(y));
  return sel ? __int_as_float(x) : __int_as_float(y);
}

// ---------------------------------------------------------------------------
// Kernel 2: sequential scan, ONE row per wave (round-2 lesson: same-wave row
// packing serializes chains), EIGHT waves per block so each SIMD hosts 2
// independent hardware waves -- SMT fills whatever per-wave pipeline/fetch
// stalls exist. Chain per step (target ~19 links):
//   gather(2) -> fma(4, 8 accumulators) -> tree(2) -> sw16(4) -> sw32(4)
//   -> exp(1) -> +1(1) -> rcp(1) -> fma(1)
// ---------------------------------------------------------------------------
__global__ __launch_bounds__(64 * WPB, 2)
void scan_kernel(
    const int* __restrict__ tok, const float* __restrict__ P,
    const float* __restrict__ Whh, const float* __restrict__ Wout,
    const float* __restrict__ bout, float* __restrict__ out) {
  const int lane = threadIdx.x & 63;
  const int row  = blockIdx.x * WPB + (threadIdx.x >> 6);

  // ---- calibration: gather permutation + swap register-select ----
  int gcal[16];
  GATHER_ROW(lane, gcal);  // gcal[s] = source lane (== unit index) of slot s

  int x16 = lane, y16 = lane;
  asm volatile("s_nop 1\n\tv_permlane16_swap_b32 %0, %1" : "+v"(x16), "+v"(y16));
  const bool sel16 = (x16 == (lane ^ 16));
  int x32 = lane, y32 = lane;
  asm volatile("s_nop 1\n\tv_permlane32_swap_b32 %0, %1" : "+v"(x32), "+v"(y32));
  const bool sel32 = (x32 == (lane ^ 32));

  // ---- weights: 4 columns (lane, ^16, ^32, ^48) x own-row 16 inputs,
  // permuted to gather order, pre-scaled by SC, pinned in VGPRs ----
  const int c0 = lane, c1 = lane ^ 16, c2 = lane ^ 32, c3 = lane ^ 48;
  v2f w0[8], w1[8], w2[8], w3[8];
#pragma unroll
  for (int s = 0; s < 8; ++s) {
    const int i0 = gcal[2 * s] * UNITS, i1 = gcal[2 * s + 1] * UNITS;
    float t00 = SC * Whh[i0 + c0], t01 = SC * Whh[i1 + c0];
    float t10 = SC * Whh[i0 + c1], t11 = SC * Whh[i1 + c1];
    float t20 = SC * Whh[i0 + c2], t21 = SC * Whh[i1 + c2];
    float t30 = SC * Whh[i0 + c3], t31 = SC * Whh[i1 + c3];
    asm volatile("" : "+v"(t00), "+v"(t01), "+v"(t10), "+v"(t11));
    asm volatile("" : "+v"(t20), "+v"(t21), "+v"(t30), "+v"(t31));
    w0[s].x = t00; w0[s].y = t01;  w1[s].x = t10; w1[s].y = t11;
    w2[s].x = t20; w2[s].y = t21;  w3[s].x = t30; w3[s].y = t31;
  }

  // ---- all 512 tokens of this row, pre-scaled by UNITS (coalesced) ----
  int tokv[SEQ / 64];
  const int* trow = tok + (long)row * SEQ;
#pragma unroll
  for (int c = 0; c < SEQ / 64; ++c) {
    int t = trow[c * 64 + lane] * UNITS;
    asm volatile("" : "+v"(t));
    tokv[c] = t;
  }

  float h = 0.f;

  // distance-2 P prefetch ring (consumed ~2 steps after issue; covers L2 hit).
  float a0 = P[(long)__builtin_amdgcn_readlane(tokv[0], 0) + lane];
  float a1 = P[(long)__builtin_amdgcn_readlane(tokv[0], 1) + lane];

#pragma unroll
  for (int c = 0; c < SEQ / 64; ++c) {
#pragma unroll 2
    for (int tt = 0; tt < 64; ++tt) {
      float a_cur = a0;
      a0 = a1;
      int tkn = __builtin_amdgcn_readlane(tokv[c], (tt + 2) & 63);
      a1 = P[(long)tkn + lane];  // garbage at tt=62,63; patched below

      // ---- in-register all-gather of h across own 16-lane row ----
      int gi[16];
      GATHER_ROW(__float_as_int(h), gi);

      // ---- 4 column partials, 8 accumulators (4-deep pk_fma chains);
      // a_cur folded into own-column acc init ----
      v2f a0A, a0B = {0.f, 0.f}, a1A = {0.f, 0.f}, a1B = {0.f, 0.f};
      v2f a2A = {0.f, 0.f}, a2B = {0.f, 0.f}, a3A = {0.f, 0.f}, a3B = {0.f, 0.f};
      a0A.x = a_cur; a0A.y = 0.f;
#pragma unroll
      for (int q = 0; q < 8; ++q) {
        v2f gp;
        gp.x = __int_as_float(gi[2 * q]);
        gp.y = __int_as_float(gi[2 * q + 1]);
        if (q & 1) {
          a0B += gp * w0[q]; a1B += gp * w1[q];
          a2B += gp * w2[q]; a3B += gp * w3[q];
        } else {
          a0A += gp * w0[q]; a1A += gp * w1[q];
          a2A += gp * w2[q]; a3A += gp * w3[q];
        }
      }
      v2f r0 = a0A + a0B, r1 = a1A + a1B, r2 = a2A + a2B, r3 = a3A + a3B;
      float p0 = r0.x + r0.y;   // col lane      (incl. a_cur)
      float p1 = r1.x + r1.y;   // col lane^16
      float p2 = r2.x + r2.y;   // col lane^32
      float p3 = r3.x + r3.y;   // col lane^48

      // combine: y[j] = P0(j) + P1(j^16) + P2(j^32) + P3(j^48); yv = SC * s
      float s1 = p0 + sw16(p1, sel16);
      float s2 = p2 + sw16(p3, sel16);
      float yv = s1 + sw32(s2, sel32);

      // tanh(s) = 1 - 2/(e^{2s}+1);  e^{2s} = 2^yv (SC prescale)
      float ex; asm("v_exp_f32 %0, %1\n\ts_nop 1" : "=v"(ex) : "v"(yv));
      float t1 = ex + 1.f;
      float rc; asm("v_rcp_f32 %0, %1\n\ts_nop 1" : "=v"(rc) : "v"(t1));
      h = __builtin_fmaf(-2.f, rc, 1.f);
    }
    if (c + 1 < SEQ / 64) {  // restore ring invariant for next chunk
      a0 = P[(long)__builtin_amdgcn_readlane(tokv[c + 1], 0) + lane];
      a1 = P[(long)__builtin_amdgcn_readlane(tokv[c + 1], 1) + lane];
    }
  }

  // out[row] = sigmoid(sum_j h[j]*Wout[j] + bout)
  float p = h * Wout[lane];
#pragma unroll
  for (int off = 32; off > 0; off >>= 1) p += __shfl_xor(p, off);
  if (lane == 0) out[row] = 1.f / (1.f + __expf(-(p + bout[0])));
}

extern "C" void kernel_launch(void* const* d_in, const int* in_sizes, int n_in,
                              void* d_out, int out_size, void* d_ws, size_t ws_size,
                              hipStream_t stream) {
  const int*   tok  = (const int*)  d_in[0];  // [BATCH, SEQ] int32
  const float* emb  = (const float*)d_in[1];  // [VOCAB, EMB]
  const float* Wxh  = (const float*)d_in[2];  // [EMB, UNITS]
  const float* Whh  = (const float*)d_in[3];  // [UNITS, UNITS]
  const float* bias = (const float*)d_in[4];  // [UNITS]
  const float* Wout = (const float*)d_in[5];  // [UNITS, 1]
  const float* bout = (const float*)d_in[6];  // [1]
  float* out = (float*)d_out;                 // [BATCH, 1] fp32

  float* P = (float*)d_ws;                    // VOCAB*UNITS fp32 = 256 KB

  proj_kernel<<<VOCAB, 64, 0, stream>>>(emb, Wxh, bias, P);
  scan_kernel<<<BATCH / WPB, 64 * WPB, 0, stream>>>(tok, P, Whh, Wout, bout, out);
}

// Round 4
// 111.013 us; speedup vs baseline: 1.8337x; 1.5531x over previous
//
#include <hip/hip_runtime.h>

#define BATCH 512
#define SEQ   512
#define VOCAB 1000
#define EMB   100
#define UNITS 64
#define SC    2.88539008177792681f   // 2*log2(e): v_exp_f32(SC*s) == e^{2s}

typedef float v2f __attribute__((ext_vector_type(2)));

// ---------------------------------------------------------------------------
// Kernel 1: P[v][u] = SC*(sum_d emb[v][d] * Wxh[d][u] + b[u])   (VOCAB x UNITS)
// SC = 2*log2(e) pre-scale: the scan feeds y straight into v_exp_f32 (2^y)
// for tanh(s) = 1 - 2/(e^{2s}+1), removing the dependent mul before exp.
// ---------------------------------------------------------------------------
__global__ __launch_bounds__(64) void proj_kernel(
    const float* __restrict__ emb, const float* __restrict__ Wxh,
    const float* __restrict__ bias, float* __restrict__ P) {
  const int v = blockIdx.x;
  const int u = threadIdx.x;
  const float* e = emb + v * EMB;
  float acc = bias[u];
#pragma unroll 5
  for (int d = 0; d < EMB; ++d) acc += e[d] * Wxh[d * UNITS + u];
  P[v * UNITS + u] = SC * acc;
}

// ---------------------------------------------------------------------------
// DPP all-gather of one value/lane across the lane's own 16-lane row.
// 4 quad_perm broadcasts + row_ror 4/8/12 cover all 16 row values for EITHER
// rotate direction; exact slot->source-lane permutation is calibrated at
// runtime (on lane_id) and folded into the weight layout.
// ---------------------------------------------------------------------------
#define DPP_I(src, ctrl) __builtin_amdgcn_update_dpp(0, (src), (ctrl), 0xF, 0xF, true)

#define GATHER_ROW(v_, g_)                                          \
  do {                                                              \
    g_[0] = DPP_I((v_), 0x00);  /* quad_perm:[0,0,0,0] */           \
    g_[1] = DPP_I((v_), 0x55);  /* quad_perm:[1,1,1,1] */           \
    g_[2] = DPP_I((v_), 0xAA);  /* quad_perm:[2,2,2,2] */           \
    g_[3] = DPP_I((v_), 0xFF);  /* quad_perm:[3,3,3,3] */           \
    g_[4]  = DPP_I(g_[0], 0x124); g_[5]  = DPP_I(g_[1], 0x124);     \
    g_[6]  = DPP_I(g_[2], 0x124); g_[7]  = DPP_I(g_[3], 0x124);     \
    g_[8]  = DPP_I(g_[0], 0x128); g_[9]  = DPP_I(g_[1], 0x128);     \
    g_[10] = DPP_I(g_[2], 0x128); g_[11] = DPP_I(g_[3], 0x128);     \
    g_[12] = DPP_I(g_[0], 0x12C); g_[13] = DPP_I(g_[1], 0x12C);     \
    g_[14] = DPP_I(g_[2], 0x12C); g_[15] = DPP_I(g_[3], 0x12C);     \
  } while (0)

// lane^16 / lane^32 exchange on the VALU pipe; duplicate-then-swap guarantees
// (for any block-swap semantics) that each lane holds the partner value in
// exactly one of the two regs; 'sel' (calibrated on lane_id) picks it.
__device__ __forceinline__ float sw16(float v, bool sel) {
  int x = __float_as_int(v), y = x;
  asm volatile("s_nop 1\n\tv_permlane16_swap_b32 %0, %1" : "+v"(x), "+v"(y));
  return sel ? __int_as_float(x) : __int_as_float(y);
}
__device__ __forceinline__ float sw32(float v, bool sel) {
  int x = __float_as_int(v), y = x;
  asm volatile("s_nop 1\n\tv_permlane32_swap_b32 %0, %1" : "+v"(x), "+v"(y));
  return sel ? __int_as_float(x) : __int_as_float(y);
}

// ---------------------------------------------------------------------------
// Kernel 2: sequential scan, ONE row per wave, 64-thread blocks, grid=512
// (round-1 config: VGPR budget 512, weights stay pinned -- round-3's
// 512-thread blocks made the compiler spill to 56 VGPRs).  Chain per step:
//   gather(2) -> pk_fma(4, 8 accumulators) -> tree(3+1) -> sw16(2) -> add
//   -> sw32(2) -> add -> exp(1) -> add(1) -> rcp(1) -> fma(1)   (~19 links)
// ---------------------------------------------------------------------------
__global__ __launch_bounds__(64)
__attribute__((amdgpu_waves_per_eu(1, 1)))
void scan_kernel(
    const int* __restrict__ tok, const float* __restrict__ P,
    const float* __restrict__ Whh, const float* __restrict__ Wout,
    const float* __restrict__ bout, float* __restrict__ out) {
  const int row  = blockIdx.x;
  const int lane = threadIdx.x;

  // ---- calibration: gather permutation + swap register-select ----
  int gcal[16];
  GATHER_ROW(lane, gcal);  // gcal[s] = source lane (== unit index) of slot s

  int x16 = lane, y16 = lane;
  asm volatile("s_nop 1\n\tv_permlane16_swap_b32 %0, %1" : "+v"(x16), "+v"(y16));
  const bool sel16 = (x16 == (lane ^ 16));
  int x32 = lane, y32 = lane;
  asm volatile("s_nop 1\n\tv_permlane32_swap_b32 %0, %1" : "+v"(x32), "+v"(y32));
  const bool sel32 = (x32 == (lane ^ 32));

  // ---- weights: 4 columns (lane, ^16, ^32, ^48) x own-row 16 inputs,
  // permuted to gather order, pre-scaled by SC, pinned in VGPRs ----
  const int c0 = lane, c1 = lane ^ 16, c2 = lane ^ 32, c3 = lane ^ 48;
  v2f w0[8], w1[8], w2[8], w3[8];
#pragma unroll
  for (int s = 0; s < 8; ++s) {
    const int i0 = gcal[2 * s] * UNITS, i1 = gcal[2 * s + 1] * UNITS;
    float t00 = SC * Whh[i0 + c0], t01 = SC * Whh[i1 + c0];
    float t10 = SC * Whh[i0 + c1], t11 = SC * Whh[i1 + c1];
    float t20 = SC * Whh[i0 + c2], t21 = SC * Whh[i1 + c2];
    float t30 = SC * Whh[i0 + c3], t31 = SC * Whh[i1 + c3];
    asm volatile("" : "+v"(t00), "+v"(t01), "+v"(t10), "+v"(t11));
    asm volatile("" : "+v"(t20), "+v"(t21), "+v"(t30), "+v"(t31));
    w0[s].x = t00; w0[s].y = t01;  w1[s].x = t10; w1[s].y = t11;
    w2[s].x = t20; w2[s].y = t21;  w3[s].x = t30; w3[s].y = t31;
  }

  // ---- all 512 tokens of this row, pre-scaled by UNITS (coalesced) ----
  int tokv[SEQ / 64];
  const int* trow = tok + (long)row * SEQ;
#pragma unroll
  for (int c = 0; c < SEQ / 64; ++c) {
    int t = trow[c * 64 + lane] * UNITS;
    asm volatile("" : "+v"(t));
    tokv[c] = t;
  }

  float h = 0.f;

  // distance-2 P prefetch ring (consumed ~2 steps after issue; covers L2 hit).
  float a0 = P[(long)__builtin_amdgcn_readlane(tokv[0], 0) + lane];
  float a1 = P[(long)__builtin_amdgcn_readlane(tokv[0], 1) + lane];

#pragma unroll
  for (int c = 0; c < SEQ / 64; ++c) {
#pragma unroll 2
    for (int tt = 0; tt < 64; ++tt) {
      float a_cur = a0;
      a0 = a1;
      int tkn = __builtin_amdgcn_readlane(tokv[c], (tt + 2) & 63);
      a1 = P[(long)tkn + lane];  // garbage at tt=62,63; patched below

      // ---- in-register all-gather of h across own 16-lane row ----
      int gi[16];
      GATHER_ROW(__float_as_int(h), gi);

      // ---- 4 column partials, 8 accumulators (4-deep pk_fma chains);
      // a_cur folded into own-column acc init ----
      v2f a0A, a0B = {0.f, 0.f}, a1A = {0.f, 0.f}, a1B = {0.f, 0.f};
      v2f a2A = {0.f, 0.f}, a2B = {0.f, 0.f}, a3A = {0.f, 0.f}, a3B = {0.f, 0.f};
      a0A.x = a_cur; a0A.y = 0.f;
#pragma unroll
      for (int q = 0; q < 8; ++q) {
        v2f gp;
        gp.x = __int_as_float(gi[2 * q]);
        gp.y = __int_as_float(gi[2 * q + 1]);
        if (q & 1) {
          a0B += gp * w0[q]; a1B += gp * w1[q];
          a2B += gp * w2[q]; a3B += gp * w3[q];
        } else {
          a0A += gp * w0[q]; a1A += gp * w1[q];
          a2A += gp * w2[q]; a3A += gp * w3[q];
        }
      }
      v2f r0 = a0A + a0B, r1 = a1A + a1B, r2 = a2A + a2B, r3 = a3A + a3B;
      float p0 = r0.x + r0.y;   // col lane      (incl. a_cur)
      float p1 = r1.x + r1.y;   // col lane^16
      float p2 = r2.x + r2.y;   // col lane^32
      float p3 = r3.x + r3.y;   // col lane^48

      // combine: y[j] = P0(j) + P1(j^16) + P2(j^32) + P3(j^48); yv = SC * s
      float s1 = p0 + sw16(p1, sel16);
      float s2 = p2 + sw16(p3, sel16);
      float yv = s1 + sw32(s2, sel32);

      // tanh(s) = 1 - 2/(e^{2s}+1);  e^{2s} = 2^yv (SC prescale)
      float ex; asm("v_exp_f32 %0, %1\n\ts_nop 1" : "=v"(ex) : "v"(yv));
      float t1 = ex + 1.f;
      float rc; asm("v_rcp_f32 %0, %1\n\ts_nop 1" : "=v"(rc) : "v"(t1));
      h = __builtin_fmaf(-2.f, rc, 1.f);
    }
    if (c + 1 < SEQ / 64) {  // restore ring invariant for next chunk
      a0 = P[(long)__builtin_amdgcn_readlane(tokv[c + 1], 0) + lane];
      a1 = P[(long)__builtin_amdgcn_readlane(tokv[c + 1], 1) + lane];
    }
  }

  // out[row] = sigmoid(sum_j h[j]*Wout[j] + bout)
  float p = h * Wout[lane];
#pragma unroll
  for (int off = 32; off > 0; off >>= 1) p += __shfl_xor(p, off);
  if (lane == 0) out[row] = 1.f / (1.f + __expf(-(p + bout[0])));
}

extern "C" void kernel_launch(void* const* d_in, const int* in_sizes, int n_in,
                              void* d_out, int out_size, void* d_ws, size_t ws_size,
                              hipStream_t stream) {
  const int*   tok  = (const int*)  d_in[0];  // [BATCH, SEQ] int32
  const float* emb  = (const float*)d_in[1];  // [VOCAB, EMB]
  const float* Wxh  = (const float*)d_in[2];  // [EMB, UNITS]
  const float* Whh  = (const float*)d_in[3];  // [UNITS, UNITS]
  const float* bias = (const float*)d_in[4];  // [UNITS]
  const float* Wout = (const float*)d_in[5];  // [UNITS, 1]
  const float* bout = (const float*)d_in[6];  // [1]
  float* out = (float*)d_out;                 // [BATCH, 1] fp32

  float* P = (float*)d_ws;                    // VOCAB*UNITS fp32 = 256 KB

  proj_kernel<<<VOCAB, 64, 0, stream>>>(emb, Wxh, bias, P);
  scan_kernel<<<BATCH, 64, 0, stream>>>(tok, P, Whh, Wout, bout, out);
}